// Round 6
// baseline (1116.733 us; speedup 1.0000x reference)
//
#include <hip/hip_runtime.h>
#include <hip/hip_fp16.h>
#include <hip/hip_cooperative_groups.h>
#include <math.h>

namespace cg = cooperative_groups;

#define NN 100000
#define NE 3200000
#define CF 512

#define NPARTS  8
#define PART    12500              // nodes per partition (50 KB LDS hist)
#define NSLICES 64                 // edge slices
#define EPB     (NE / NSLICES)     // 50000 edges per block
#define NPB     (NSLICES * NPARTS) // 512 blocks -> exactly 2 blocks/CU
#define NODES_PER_BLK 196          // 512*196 = 100352 >= NN

// ---- ws layout (bytes) ----
// part : u16/half [NPB][PART] @ 0          (12,800,000) -- deg(u16) then s(half)
// g    : float[NN]            @ 12,800,000
// h    : float[NN]            @ 13,200,000  (fallback path only)
// dinv : float[NN]            @ 13,600,000  (fallback path only)
#define OFF_G    12800000
#define OFF_H    13200000
#define OFF_DINV 13600000

// Per-wave int64-layout self-detect (high words of int64 edge values are 0).
__device__ __forceinline__ bool detect_f64(const int* e32) {
    unsigned v = ((const unsigned*)e32)[2 * (threadIdx.x & 63) + 1];
    return __ballot(v != 0u) == 0ULL;
}

__device__ __forceinline__ int4 load_col4(const int* e32, bool f64, int e) {
    if (f64) {
        const int4* q = (const int4*)(e32 + 2 * (NE + e));
        int4 a = q[0], b = q[1];
        return make_int4(a.x, a.z, b.x, b.z);
    }
    return *(const int4*)(e32 + NE + e);
}
__device__ __forceinline__ int4 load_row4(const int* e32, bool f64, int e) {
    if (f64) {
        const int4* q = (const int4*)(e32 + 2 * e);
        int4 a = q[0], b = q[1];
        return make_int4(a.x, a.z, b.x, b.z);
    }
    return *(const int4*)(e32 + e);
}

// ---------------------------------------------------------------------------
// Single cooperative kernel: P0 deg-hist + h  |sync|  P1 dinv+g  |sync|
//                            P2 scatter       |sync|  P3 final
// Phases are the R1-proven structures verbatim; ONLY the launch structure
// changed (4 launches -> 1 cooperative dispatch). 51.6 KB static LDS +
// __launch_bounds__(1024,8) -> 2 blocks/CU, all 512 blocks co-resident.
// ---------------------------------------------------------------------------
__global__ __launch_bounds__(1024, 8) void gcn_fused(const int* e32, const float* x,
                                                     const float* W, const float* bias,
                                                     unsigned short* part_u16,
                                                     __half* part_h,
                                                     float* g, float* out) {
    __shared__ int hist[PART];                 // reused as float in P2
    __shared__ float h_lds[NODES_PER_BLK];
    __shared__ float dinv_lds[NODES_PER_BLK];
    cg::grid_group grid = cg::this_grid();

    int tid = threadIdx.x;
    int blk = blockIdx.x;
    int w = tid >> 6, lane = tid & 63;
    bool f64 = detect_f64(e32);
    int p = blk >> 6, s = blk & 63;
    int lo = p * PART, base = s * EPB;

    // ---- P0: waves 0-11 deg histogram; waves 12-15 h = x @ W^T ----
    for (int i = tid; i < PART; i += 1024) hist[i] = 0;
    __syncthreads();
    if (w < 12) {
        for (int e = base + tid * 4; e < base + EPB; e += 3072) {
            int4 c = load_col4(e32, f64, e);
            unsigned l0 = (unsigned)(c.x - lo), l1 = (unsigned)(c.y - lo);
            unsigned l2 = (unsigned)(c.z - lo), l3 = (unsigned)(c.w - lo);
            if (l0 < PART) atomicAdd(&hist[l0], 1);
            if (l1 < PART) atomicAdd(&hist[l1], 1);
            if (l2 < PART) atomicAdd(&hist[l2], 1);
            if (l3 < PART) atomicAdd(&hist[l3], 1);
        }
    } else {
        const float4* Wr = (const float4*)W;
        float4 w0 = Wr[lane], w1 = Wr[lane + 64];  // invariant
        int start = blk * NODES_PER_BLK;
        int end = start + NODES_PER_BLK;
        for (int i = start + (w - 12) * 2; i < end; i += 8) {
            int i1 = i + 1;
            float s0 = 0.f, s1 = 0.f;
            if (i < NN) {
                const float4* xr = (const float4*)(x + (size_t)i * CF);
                float4 a = xr[lane], bq = xr[lane + 64];
                s0 = a.x * w0.x + a.y * w0.y + a.z * w0.z + a.w * w0.w
                   + bq.x * w1.x + bq.y * w1.y + bq.z * w1.z + bq.w * w1.w;
            }
            if (i1 < NN) {
                const float4* xr = (const float4*)(x + (size_t)i1 * CF);
                float4 a = xr[lane], bq = xr[lane + 64];
                s1 = a.x * w0.x + a.y * w0.y + a.z * w0.z + a.w * w0.w
                   + bq.x * w1.x + bq.y * w1.y + bq.z * w1.z + bq.w * w1.w;
            }
#pragma unroll
            for (int off = 32; off >= 1; off >>= 1) {
                s0 += __shfl_down(s0, off, 64);
                s1 += __shfl_down(s1, off, 64);
            }
            if (lane == 0) {
                h_lds[i - start] = s0;
                h_lds[i1 - start] = s1;
            }
        }
    }
    __syncthreads();
    {
        unsigned short* outp = part_u16 + (size_t)blk * PART;
        for (int i = tid; i < PART; i += 1024) outp[i] = (unsigned short)hist[i];
    }
    __threadfence();
    grid.sync();

    // ---- P1: dinv + g for this block's node range ----
    int node = blk * NODES_PER_BLK + tid;
    if (tid < NODES_PER_BLK && node < NN) {
        int pp = node / PART, l = node - pp * PART;
        const unsigned short* bp = part_u16 + ((size_t)(pp << 6)) * PART + l;
        int d = 1;
#pragma unroll 16
        for (int ss = 0; ss < NSLICES; ++ss) d += bp[(size_t)ss * PART];
        float di = rsqrtf((float)d);
        dinv_lds[tid] = di;
        g[node] = h_lds[tid] * di;
    }
    __threadfence();
    grid.sync();

    // ---- P2: scatter s[col] += g[row] (all 16 waves) ----
    float* histf = (float*)hist;
    for (int i = tid; i < PART; i += 1024) histf[i] = 0.f;
    __syncthreads();
    for (int e = base + tid * 4; e < base + EPB; e += 4096) {
        int4 c = load_col4(e32, f64, e);
        int4 r = load_row4(e32, f64, e);
        unsigned l0 = (unsigned)(c.x - lo), l1 = (unsigned)(c.y - lo);
        unsigned l2 = (unsigned)(c.z - lo), l3 = (unsigned)(c.w - lo);
        if (l0 < PART) atomicAdd(&histf[l0], g[r.x]);
        if (l1 < PART) atomicAdd(&histf[l1], g[r.y]);
        if (l2 < PART) atomicAdd(&histf[l2], g[r.z]);
        if (l3 < PART) atomicAdd(&histf[l3], g[r.w]);
    }
    __syncthreads();
    {
        __half* outp = part_h + (size_t)blk * PART;
        for (int i = tid; i < PART; i += 1024) outp[i] = __float2half(histf[i]);
    }
    __threadfence();
    grid.sync();

    // ---- P3: final ----
    if (tid < NODES_PER_BLK && node < NN) {
        int pp = node / PART, l = node - pp * PART;
        const __half* bp = part_h + ((size_t)(pp << 6)) * PART + l;
        float acc = g[node];
#pragma unroll 16
        for (int ss = 0; ss < NSLICES; ++ss) acc += __half2float(bp[(size_t)ss * PART]);
        float v = dinv_lds[tid] * acc + bias[0];
        out[node] = 1.f / (1.f + expf(-v));
    }
}

// ===========================================================================
// Fallback path (non-cooperative, R1 replica), used only if coop launch fails.
// ===========================================================================
__global__ __launch_bounds__(1024) void deg_h_kernel(const int* __restrict__ e32,
                                                     const float* __restrict__ x,
                                                     const float* __restrict__ W,
                                                     unsigned short* __restrict__ deg_part,
                                                     float* __restrict__ h) {
    __shared__ int hist[PART];
    int tid = threadIdx.x;
    for (int i = tid; i < PART; i += 1024) hist[i] = 0;
    __syncthreads();
    int w = tid >> 6, lane = tid & 63;
    if (w < 12) {
        bool f64 = detect_f64(e32);
        int p = blockIdx.x >> 6;
        int s = blockIdx.x & 63;
        int lo = p * PART;
        int base = s * EPB;
        for (int e = base + tid * 4; e < base + EPB; e += 3072) {
            int4 c = load_col4(e32, f64, e);
            unsigned l0 = (unsigned)(c.x - lo), l1 = (unsigned)(c.y - lo);
            unsigned l2 = (unsigned)(c.z - lo), l3 = (unsigned)(c.w - lo);
            if (l0 < PART) atomicAdd(&hist[l0], 1);
            if (l1 < PART) atomicAdd(&hist[l1], 1);
            if (l2 < PART) atomicAdd(&hist[l2], 1);
            if (l3 < PART) atomicAdd(&hist[l3], 1);
        }
    } else {
        const float4* Wr = (const float4*)W;
        float4 w0 = Wr[lane], w1 = Wr[lane + 64];
        int start = blockIdx.x * NODES_PER_BLK;
        int end = start + NODES_PER_BLK;
        for (int i = start + (w - 12) * 2; i < end; i += 8) {
            int i1 = i + 1;
            float s0 = 0.f, s1 = 0.f;
            if (i < NN) {
                const float4* xr = (const float4*)(x + (size_t)i * CF);
                float4 a = xr[lane], bq = xr[lane + 64];
                s0 = a.x * w0.x + a.y * w0.y + a.z * w0.z + a.w * w0.w
                   + bq.x * w1.x + bq.y * w1.y + bq.z * w1.z + bq.w * w1.w;
            }
            if (i1 < NN) {
                const float4* xr = (const float4*)(x + (size_t)i1 * CF);
                float4 a = xr[lane], bq = xr[lane + 64];
                s1 = a.x * w0.x + a.y * w0.y + a.z * w0.z + a.w * w0.w
                   + bq.x * w1.x + bq.y * w1.y + bq.z * w1.z + bq.w * w1.w;
            }
#pragma unroll
            for (int off = 32; off >= 1; off >>= 1) {
                s0 += __shfl_down(s0, off, 64);
                s1 += __shfl_down(s1, off, 64);
            }
            if (lane == 0) {
                if (i < NN) h[i] = s0;
                if (i1 < NN) h[i1] = s1;
            }
        }
    }
    __syncthreads();
    unsigned short* outp = deg_part + (size_t)blockIdx.x * PART;
    for (int i = tid; i < PART; i += 1024) outp[i] = (unsigned short)hist[i];
}

__global__ void dinv_g_kernel(const unsigned short* __restrict__ deg_part,
                              const float* __restrict__ h,
                              float* __restrict__ dinv,
                              float* __restrict__ g) {
    int i = blockIdx.x * blockDim.x + threadIdx.x;
    if (i >= NN) return;
    int p = i / PART, l = i - p * PART;
    const unsigned short* bp = deg_part + ((size_t)(p << 6)) * PART + l;
    int d = 1;
#pragma unroll
    for (int s = 0; s < NSLICES; ++s) d += bp[(size_t)s * PART];
    float di = rsqrtf((float)d);
    dinv[i] = di;
    g[i] = h[i] * di;
}

__global__ __launch_bounds__(1024) void scatter_lds_kernel(const int* __restrict__ e32,
                                                           const float* __restrict__ g,
                                                           __half* __restrict__ s_part) {
    __shared__ float hs[PART];
    int tid = threadIdx.x;
    for (int i = tid; i < PART; i += 1024) hs[i] = 0.f;
    __syncthreads();
    bool f64 = detect_f64(e32);
    int p = blockIdx.x >> 6;
    int s = blockIdx.x & 63;
    int lo = p * PART;
    int base = s * EPB;
    for (int e = base + tid * 4; e < base + EPB; e += 4096) {
        int4 c = load_col4(e32, f64, e);
        int4 r = load_row4(e32, f64, e);
        unsigned l0 = (unsigned)(c.x - lo), l1 = (unsigned)(c.y - lo);
        unsigned l2 = (unsigned)(c.z - lo), l3 = (unsigned)(c.w - lo);
        if (l0 < PART) atomicAdd(&hs[l0], g[r.x]);
        if (l1 < PART) atomicAdd(&hs[l1], g[r.y]);
        if (l2 < PART) atomicAdd(&hs[l2], g[r.z]);
        if (l3 < PART) atomicAdd(&hs[l3], g[r.w]);
    }
    __syncthreads();
    __half* outp = s_part + (size_t)blockIdx.x * PART;
    for (int i = tid; i < PART; i += 1024) outp[i] = __float2half(hs[i]);
}

__global__ void final_kernel(const __half* __restrict__ s_part,
                             const float* __restrict__ g,
                             const float* __restrict__ dinv,
                             const float* __restrict__ b,
                             float* __restrict__ out) {
    int i = blockIdx.x * blockDim.x + threadIdx.x;
    if (i >= NN) return;
    int p = i / PART, l = i - p * PART;
    const __half* bp = s_part + ((size_t)(p << 6)) * PART + l;
    float acc = g[i];
#pragma unroll
    for (int s = 0; s < NSLICES; ++s) acc += __half2float(bp[(size_t)s * PART]);
    float v = dinv[i] * acc + b[0];
    out[i] = 1.f / (1.f + expf(-v));
}

extern "C" void kernel_launch(void* const* d_in, const int* in_sizes, int n_in,
                              void* d_out, int out_size, void* d_ws, size_t ws_size,
                              hipStream_t stream) {
    const float* x = (const float*)d_in[0];
    const int* eidx = (const int*)d_in[1];
    const float* W = (const float*)d_in[2];
    const float* b = (const float*)d_in[3];
    float* out = (float*)d_out;

    char* ws = (char*)d_ws;
    unsigned short* part_u16 = (unsigned short*)(ws);  // deg partials (reused as half)
    __half* part_h = (__half*)(ws);
    float* g = (float*)(ws + OFF_G);
    float* h = (float*)(ws + OFF_H);
    float* dinv = (float*)(ws + OFF_DINV);

    void* kargs[] = {(void*)&eidx, (void*)&x, (void*)&W, (void*)&b,
                     (void*)&part_u16, (void*)&part_h, (void*)&g, (void*)&out};
    hipError_t err = hipLaunchCooperativeKernel((const void*)gcn_fused,
                                                dim3(NPB), dim3(1024),
                                                kargs, 0, stream);
    if (err != hipSuccess) {
        // Fallback: 4 separate launches (R1 structure, known-passing)
        deg_h_kernel<<<NPB, 1024, 0, stream>>>(eidx, x, W, part_u16, h);
        dinv_g_kernel<<<(NN + 255) / 256, 256, 0, stream>>>(part_u16, h, dinv, g);
        scatter_lds_kernel<<<NPB, 1024, 0, stream>>>(eidx, g, part_h);
        final_kernel<<<(NN + 255) / 256, 256, 0, stream>>>(part_h, g, dinv, b, out);
    }
}

// Round 7
// 553.883 us; speedup vs baseline: 2.0162x; 2.0162x over previous
//
#include <hip/hip_runtime.h>
#include <hip/hip_fp16.h>
#include <math.h>

#define NN 100000
#define NE 3200000
#define CF 512

// ---- deg pass geometry (R1-proven, verbatim) ----
#define NPARTS  8
#define PART    12500              // nodes per partition (50 KB LDS hist)
#define NSLICES 64                 // edge slices (deg)
#define EPB     (NE / NSLICES)     // 50000 edges per deg block
#define NPB     (NSLICES * NPARTS) // 512 blocks
#define NODES_PER_BLK 196          // GEMV: 512*196 >= NN

// ---- scatter pass geometry (new: fewer slices, fused final) ----
#define SNSL    32                 // scatter slices
#define SEPB    (NE / SNSL)        // 100000 edges per scatter block
#define SNPB    (SNSL * NPARTS)    // 256 blocks

// ---- ws layout (bytes) ----
// dpart : u16 [NPB][PART]  @ 0           (12,800,000)
// spart : half [SNPB][PART]@ 12,800,000  (6,400,000)
// g     : f32[NN]          @ 19,200,000
// h     : f32[NN]          @ 19,600,000
// dinv  : f32[NN]          @ 20,000,000
// ctr   : u32[8]           @ 20,400,000
#define OFF_SPART 12800000
#define OFF_G     19200000
#define OFF_H     19600000
#define OFF_DINV  20000000
#define OFF_CTR   20400000

// Per-wave int64-layout self-detect (high words of int64 edge values are 0).
__device__ __forceinline__ bool detect_f64(const int* e32) {
    unsigned v = ((const unsigned*)e32)[2 * (threadIdx.x & 63) + 1];
    return __ballot(v != 0u) == 0ULL;
}

__device__ __forceinline__ int4 load_col4(const int* e32, bool f64, int e) {
    if (f64) {
        const int4* q = (const int4*)(e32 + 2 * (NE + e));
        int4 a = q[0], b = q[1];
        return make_int4(a.x, a.z, b.x, b.z);
    }
    return *(const int4*)(e32 + NE + e);
}
__device__ __forceinline__ int4 load_row4(const int* e32, bool f64, int e) {
    if (f64) {
        const int4* q = (const int4*)(e32 + 2 * e);
        int4 a = q[0], b = q[1];
        return make_int4(a.x, a.z, b.x, b.z);
    }
    return *(const int4*)(e32 + e);
}

// ---------------------------------------------------------------------------
// K1 (R1-proven verbatim + ctr zeroing): waves 0-11 deg histogram over the
// block's edge slice; waves 12-15 GEMV h = x @ W^T for 196 nodes.
// ---------------------------------------------------------------------------
__global__ __launch_bounds__(1024) void deg_h_kernel(const int* __restrict__ e32,
                                                     const float* __restrict__ x,
                                                     const float* __restrict__ W,
                                                     unsigned short* __restrict__ deg_part,
                                                     float* __restrict__ h,
                                                     unsigned* __restrict__ ctr) {
    __shared__ int hist[PART];
    int tid = threadIdx.x;
    if (blockIdx.x == 0 && tid < 8) ctr[tid] = 0u;   // zero K3's counters (ws poisoned)
    for (int i = tid; i < PART; i += 1024) hist[i] = 0;
    __syncthreads();
    int w = tid >> 6, lane = tid & 63;
    if (w < 12) {
        bool f64 = detect_f64(e32);
        int p = blockIdx.x >> 6;
        int s = blockIdx.x & 63;
        int lo = p * PART;
        int base = s * EPB;
        for (int e = base + tid * 4; e < base + EPB; e += 3072) {
            int4 c = load_col4(e32, f64, e);
            unsigned l0 = (unsigned)(c.x - lo), l1 = (unsigned)(c.y - lo);
            unsigned l2 = (unsigned)(c.z - lo), l3 = (unsigned)(c.w - lo);
            if (l0 < PART) atomicAdd(&hist[l0], 1);
            if (l1 < PART) atomicAdd(&hist[l1], 1);
            if (l2 < PART) atomicAdd(&hist[l2], 1);
            if (l3 < PART) atomicAdd(&hist[l3], 1);
        }
    } else {
        const float4* Wr = (const float4*)W;
        float4 w0 = Wr[lane], w1 = Wr[lane + 64];
        int start = blockIdx.x * NODES_PER_BLK;
        int end = start + NODES_PER_BLK;
        for (int i = start + (w - 12) * 2; i < end; i += 8) {
            int i1 = i + 1;
            float s0 = 0.f, s1 = 0.f;
            if (i < NN) {
                const float4* xr = (const float4*)(x + (size_t)i * CF);
                float4 a = xr[lane], bq = xr[lane + 64];
                s0 = a.x * w0.x + a.y * w0.y + a.z * w0.z + a.w * w0.w
                   + bq.x * w1.x + bq.y * w1.y + bq.z * w1.z + bq.w * w1.w;
            }
            if (i1 < NN) {
                const float4* xr = (const float4*)(x + (size_t)i1 * CF);
                float4 a = xr[lane], bq = xr[lane + 64];
                s1 = a.x * w0.x + a.y * w0.y + a.z * w0.z + a.w * w0.w
                   + bq.x * w1.x + bq.y * w1.y + bq.z * w1.z + bq.w * w1.w;
            }
#pragma unroll
            for (int off = 32; off >= 1; off >>= 1) {
                s0 += __shfl_down(s0, off, 64);
                s1 += __shfl_down(s1, off, 64);
            }
            if (lane == 0) {
                if (i < NN) h[i] = s0;
                if (i1 < NN) h[i1] = s1;
            }
        }
    }
    __syncthreads();
    unsigned short* outp = deg_part + (size_t)blockIdx.x * PART;
    for (int i = tid; i < PART; i += 1024) outp[i] = (unsigned short)hist[i];
}

// K2 (R1-proven verbatim): dinv = rsqrt(1 + sum deg partials); g = h * dinv
__global__ void dinv_g_kernel(const unsigned short* __restrict__ deg_part,
                              const float* __restrict__ h,
                              float* __restrict__ dinv,
                              float* __restrict__ g) {
    int i = blockIdx.x * blockDim.x + threadIdx.x;
    if (i >= NN) return;
    int p = i / PART, l = i - p * PART;
    const unsigned short* bp = deg_part + ((size_t)(p << 6)) * PART + l;
    int d = 1;
#pragma unroll
    for (int s = 0; s < NSLICES; ++s) d += bp[(size_t)s * PART];
    float di = rsqrtf((float)d);
    dinv[i] = di;
    g[i] = h[i] * di;
}

// ---------------------------------------------------------------------------
// K3: scatter s[col] += g[row] (LDS-privatized, 256 blocks = NPARTS x SNSL)
// + fused final: the LAST block of each partition (ctr[p]==31) reduces the
// 32 half partials + g + dinv -> sigmoid -> out for its 12500 nodes.
// ---------------------------------------------------------------------------
__global__ __launch_bounds__(1024) void scatter_final(const int* __restrict__ e32,
                                                      const float* __restrict__ g,
                                                      const float* __restrict__ dinv,
                                                      const float* __restrict__ b,
                                                      __half* __restrict__ spart,
                                                      unsigned* __restrict__ ctr,
                                                      float* __restrict__ out) {
    __shared__ float hs[PART];
    __shared__ int lastflag;
    int tid = threadIdx.x;
    for (int i = tid; i < PART; i += 1024) hs[i] = 0.f;
    __syncthreads();

    bool f64 = detect_f64(e32);
    int p = blockIdx.x >> 5;          // 0..7
    int s = blockIdx.x & 31;          // 0..31
    int lo = p * PART;
    int base = s * SEPB;
    for (int e = base + tid * 4; e < base + SEPB; e += 4096) {
        int4 c = load_col4(e32, f64, e);
        int4 r = load_row4(e32, f64, e);
        float g0 = g[r.x], g1 = g[r.y], g2 = g[r.z], g3 = g[r.w];
        unsigned l0 = (unsigned)(c.x - lo), l1 = (unsigned)(c.y - lo);
        unsigned l2 = (unsigned)(c.z - lo), l3 = (unsigned)(c.w - lo);
        if (l0 < PART) atomicAdd(&hs[l0], g0);
        if (l1 < PART) atomicAdd(&hs[l1], g1);
        if (l2 < PART) atomicAdd(&hs[l2], g2);
        if (l3 < PART) atomicAdd(&hs[l3], g3);
    }
    __syncthreads();
    {
        __half* outp = spart + (size_t)blockIdx.x * PART;
        for (int i = tid; i < PART; i += 1024) outp[i] = __float2half(hs[i]);
    }

    // ---- last-block-per-partition fused final ----
    __threadfence();                  // release our partial writes (agent scope)
    __syncthreads();
    if (tid == 0) {
        unsigned old = atomicAdd(&ctr[p], 1u);
        lastflag = (old == (unsigned)(SNSL - 1)) ? 1 : 0;
    }
    __syncthreads();
    if (!lastflag) return;
    __threadfence();                  // acquire: invalidate caches, see all partials

    const __half* bp = spart + (size_t)(p * SNSL) * PART;
    float bias = b[0];
    for (int l = tid; l < PART; l += 1024) {
        float acc = 0.f;
#pragma unroll 8
        for (int s2 = 0; s2 < SNSL; ++s2) acc += __half2float(bp[(size_t)s2 * PART + l]);
        int i = lo + l;
        float v = dinv[i] * (acc + g[i]) + bias;
        out[i] = 1.f / (1.f + expf(-v));
    }
}

extern "C" void kernel_launch(void* const* d_in, const int* in_sizes, int n_in,
                              void* d_out, int out_size, void* d_ws, size_t ws_size,
                              hipStream_t stream) {
    const float* x = (const float*)d_in[0];
    const int* eidx = (const int*)d_in[1];
    const float* W = (const float*)d_in[2];
    const float* b = (const float*)d_in[3];
    float* out = (float*)d_out;

    char* ws = (char*)d_ws;
    unsigned short* dpart = (unsigned short*)(ws);
    __half* spart = (__half*)(ws + OFF_SPART);
    float* g = (float*)(ws + OFF_G);
    float* h = (float*)(ws + OFF_H);
    float* dinv = (float*)(ws + OFF_DINV);
    unsigned* ctr = (unsigned*)(ws + OFF_CTR);

    deg_h_kernel<<<NPB, 1024, 0, stream>>>(eidx, x, W, dpart, h, ctr);
    dinv_g_kernel<<<(NN + 255) / 256, 256, 0, stream>>>(dpart, h, dinv, g);
    scatter_final<<<SNPB, 1024, 0, stream>>>(eidx, g, dinv, b, spart, ctr, out);
}